// Round 8
// baseline (252.737 us; speedup 1.0000x reference)
//
#include <hip/hip_runtime.h>

#define B_    2
#define L_    2048
#define D_    768
#define H_    12
#define BL    4096      // B_*L_
#define BH    24        // B_*H_
#define CHUNK 128
#define NC    16        // L_/CHUNK
#define GOFF  3145728   // element offset of gate output within d_out
#define PI_F  3.14159265358979f

typedef __bf16 bf16x8 __attribute__((ext_vector_type(8)));
typedef float  f32x4  __attribute__((ext_vector_type(4)));
typedef unsigned short us8 __attribute__((ext_vector_type(8)));

__device__ __forceinline__ float bf2f(unsigned short u) {
    return __uint_as_float(((unsigned int)u) << 16);
}
__device__ __forceinline__ unsigned short f2bf(float f) {
    unsigned int u = __float_as_uint(f);
    unsigned int r = (u + 0x7fffu + ((u >> 16) & 1u)) >> 16;
    return (unsigned short)r;
}
__device__ __forceinline__ float softplusf(float x) {
    return x > 20.f ? x : log1pf(expf(x));
}
// async global->LDS, 16B per lane; LDS dest = wave-uniform base + lane*16
__device__ __forceinline__ void dma16(const unsigned short* g, unsigned short* l) {
    __builtin_amdgcn_global_load_lds(
        (const __attribute__((address_space(1))) unsigned int*)g,
        (__attribute__((address_space(3))) unsigned int*)l, 16, 0, 0);
}

// ---------------- dtype detector ----------------
__global__ __launch_bounds__(256) void detect_kernel(const unsigned short* __restrict__ x,
                                                     int* __restrict__ flag)
{
    __shared__ int cnt;
    if (threadIdx.x == 0) cnt = 0;
    __syncthreads();
    int c = 0;
    #pragma unroll
    for (int i = 0; i < 16; i++) {
        unsigned short u = x[threadIdx.x * 16 + i];
        int e = (u >> 7) & 0xff;
        if (e < 100 || e > 140) c++;
    }
    atomicAdd(&cnt, c);
    __syncthreads();
    if (threadIdx.x == 0) flag[0] = (cnt > 512) ? 1 : 0;   // 1 = inputs are fp32
}

// ---------------- prep: 6 weight transposes + bqkv/bproj converts -----------------
__global__ __launch_bounds__(256) void prep_mega_kernel(
    const void* __restrict__ s0, unsigned short* __restrict__ dq,   // Wqkv 768x2304
    const void* __restrict__ s1, unsigned short* __restrict__ dd,   // Wsd -> WdT[0]
    const void* __restrict__ s2, unsigned short* __restrict__ dsu,  // Wsu 128x1536
    const void* __restrict__ s3,                                    // Wcd -> WdT[128*768]
    const void* __restrict__ s4, unsigned short* __restrict__ dcu,  // Wcu 128x1536
    const void* __restrict__ s5, unsigned short* __restrict__ dp,   // Wproj 768x768
    const void* __restrict__ sbq, unsigned short* __restrict__ dbq, // bqkv 2304
    const void* __restrict__ sbp, unsigned short* __restrict__ dbp, // bproj 768
    const int* __restrict__ flag)
{
    int id = blockIdx.x;
    int fl = flag[0];
    if (id >= 2880) {   // small vector converts
        const void* src; unsigned short* dst; int n, base;
        if (id < 2889) { src = sbq; dst = dbq; n = 2304; base = (id - 2880) * 256; }
        else           { src = sbp; dst = dbp; n = 768;  base = (id - 2889) * 256; }
        int i = base + threadIdx.x;
        if (i < n) dst[i] = fl ? f2bf(((const float*)src)[i]) : ((const unsigned short*)src)[i];
        return;
    }
    __shared__ unsigned short tile[32][33];
    const void* src; unsigned short* dst; int K, N, tid;
    if (id < 1728)      { src = s0; dst = dq;  K = 768; N = 2304; tid = id; }
    else if (id < 1824) { src = s1; dst = dd;  K = 768; N = 128;  tid = id - 1728; }
    else if (id < 2016) { src = s2; dst = dsu; K = 128; N = 1536; tid = id - 1824; }
    else if (id < 2112) { src = s3; dst = dd + (size_t)128 * 768; K = 768; N = 128; tid = id - 2016; }
    else if (id < 2304) { src = s4; dst = dcu; K = 128; N = 1536; tid = id - 2112; }
    else                { src = s5; dst = dp;  K = 768; N = 768;  tid = id - 2304; }
    int tn = N / 32;
    int by = (tid / tn) * 32, bx = (tid % tn) * 32;
    int tx = threadIdx.x & 31, tyb = threadIdx.x >> 5;
    #pragma unroll
    for (int i = 0; i < 4; i++) {
        int k = by + tyb * 4 + i, n = bx + tx;
        size_t off = (size_t)k * N + n;
        tile[tyb * 4 + i][tx] = fl ? f2bf(((const float*)src)[off]) : ((const unsigned short*)src)[off];
    }
    __syncthreads();
    #pragma unroll
    for (int i = 0; i < 4; i++) {
        int n = bx + tyb * 4 + i, k = by + tx;
        dst[(size_t)n * K + k] = tile[tx][tyb * 4 + i];
    }
}

// ---------------- Fused convert + LayerNorm (gamma/beta read raw) -----------------
__global__ __launch_bounds__(256) void conv_ln_kernel(
    const void* __restrict__ xin,
    const void* __restrict__ gr, const void* __restrict__ br,
    unsigned short* __restrict__ x_c,
    unsigned short* __restrict__ xn,
    const int* __restrict__ flag)
{
    int row = blockIdx.x, t = threadIdx.x;
    int fl = flag[0];
    float v[3];
    #pragma unroll
    for (int j = 0; j < 3; j++) {
        int c = t + j * 256;
        v[j] = fl ? ((const float*)xin)[(size_t)row * D_ + c]
                  : bf2f(((const unsigned short*)xin)[(size_t)row * D_ + c]);
    }
    __shared__ float red[8];
    float s = v[0] + v[1] + v[2];
    #pragma unroll
    for (int m = 32; m >= 1; m >>= 1) s += __shfl_xor(s, m, 64);
    int wid = t >> 6;
    if ((t & 63) == 0) red[wid] = s;
    __syncthreads();
    float mean = (red[0] + red[1] + red[2] + red[3]) * (1.f / 768.f);
    float s2 = 0.f;
    #pragma unroll
    for (int j = 0; j < 3; j++) { float d = v[j] - mean; s2 += d * d; }
    #pragma unroll
    for (int m = 32; m >= 1; m >>= 1) s2 += __shfl_xor(s2, m, 64);
    if ((t & 63) == 0) red[4 + wid] = s2;
    __syncthreads();
    float var = (red[4] + red[5] + red[6] + red[7]) * (1.f / 768.f);
    float rs = rsqrtf(var + 1e-5f);
    #pragma unroll
    for (int j = 0; j < 3; j++) {
        int c = t + j * 256;
        float gv = fl ? ((const float*)gr)[c] : bf2f(((const unsigned short*)gr)[c]);
        float bv = fl ? ((const float*)br)[c] : bf2f(((const unsigned short*)br)[c]);
        x_c[(size_t)row * D_ + c] = f2bf(v[j]);
        float o = (v[j] - mean) * rs * gv + bv;
        xn[(size_t)row * D_ + c] = f2bf(o);
    }
}

// ---------------- MFMA GEMM v3 (round-7 structure, unchanged) ---------------------
template<int EPI>
__global__ __launch_bounds__(256) void mfma_gemm_kernel(
    const unsigned short* __restrict__ A, int lda,
    const unsigned short* __restrict__ BT,
    const unsigned short* __restrict__ bias,
    const unsigned short* __restrict__ gateb,
    void* __restrict__ outp,
    const int* __restrict__ flag,
    int N, int K)
{
    __shared__ unsigned short sbuf[17408];
    unsigned short* As = sbuf;
    unsigned short* Bs = sbuf + 8192;
    unsigned short* Cs = sbuf;

    int f = blockIdx.y * gridDim.x + blockIdx.x;
    int rps = gridDim.y >> 3;
    int strip = f & 7, within = f >> 3;
    int by = strip * rps + (within % rps);
    int bx = within / rps;
    int m0 = by * 128, n0 = bx * 128;

    int t = threadIdx.x;
    int lane = t & 63, wave = t >> 6, quad = lane >> 4, l16 = lane & 15;
    int wm = (wave & 1) * 64, wn = (wave >> 1) * 64;
    int xr = l16 & 7;

    int sr8 = lane >> 3;
    int scg = (lane & 7) ^ sr8;
    const unsigned short* ApL = A  + (size_t)(m0 + wave * 32 + sr8) * lda + scg * 8;
    const unsigned short* BpL = BT + (size_t)(n0 + wave * 32 + sr8) * K   + scg * 8;
    unsigned short* AsW = As + wave * 32 * 64;
    unsigned short* BsW = Bs + wave * 32 * 64;

    f32x4 acc[4][4];
    #pragma unroll
    for (int i = 0; i < 4; i++)
        #pragma unroll
        for (int j = 0; j < 4; j++) acc[i][j] = (f32x4){0.f, 0.f, 0.f, 0.f};

    for (int k0 = 0; k0 < K; k0 += 64) {
        __syncthreads();
        #pragma unroll
        for (int c = 0; c < 4; c++) {
            dma16(ApL + (size_t)(c * 8) * lda + k0, AsW + c * 512);
            dma16(BpL + (size_t)(c * 8) * K   + k0, BsW + c * 512);
        }
        __syncthreads();
        #pragma unroll
        for (int ks = 0; ks < 2; ks++) {
            bf16x8 af[4], bfr[4];
            #pragma unroll
            for (int i = 0; i < 4; i++)
                af[i] = *(const bf16x8*)&As[(wm + i * 16 + l16) * 64 + (((ks * 4 + quad) ^ xr) * 8)];
            #pragma unroll
            for (int j = 0; j < 4; j++)
                bfr[j] = *(const bf16x8*)&Bs[(wn + j * 16 + l16) * 64 + (((ks * 4 + quad) ^ xr) * 8)];
            #pragma unroll
            for (int i = 0; i < 4; i++)
                #pragma unroll
                for (int j = 0; j < 4; j++)
                    acc[i][j] = __builtin_amdgcn_mfma_f32_16x16x32_bf16(af[i], bfr[j], acc[i][j], 0, 0, 0);
        }
    }

    int fl = (EPI == 3) ? flag[0] : 0;
    __syncthreads();
    #pragma unroll
    for (int j = 0; j < 4; j++) {
        int col = n0 + wn + j * 16 + l16;
        float bv = bias ? bf2f(bias[col]) : 0.f;
        #pragma unroll
        for (int i = 0; i < 4; i++) {
            #pragma unroll
            for (int r = 0; r < 4; r++) {
                int row = m0 + wm + i * 16 + quad * 4 + r;
                float v = acc[i][j][r] + bv;
                if (EPI == 1) v = v / (1.f + expf(-v));
                if (EPI == 2) {
                    if (col < D_) {
                        v = v > 0.f ? v + 1.f : expf(v);
                    } else if (col < 2 * D_) {
                        float gg = bf2f(gateb[(size_t)row * D_ + (col - D_)]);
                        v *= (1.f + gg);
                        v = v > 0.f ? v + 1.f : expf(v);
                    }
                }
                if (EPI == 3 && fl) {
                    ((float*)outp)[(size_t)row * N + col] = v;
                } else {
                    Cs[(wm + i * 16 + quad * 4 + r) * 136 + wn + j * 16 + l16] = f2bf(v);
                }
            }
        }
    }
    if (!(EPI == 3 && fl)) {
        __syncthreads();
        #pragma unroll
        for (int p = 0; p < 8; p++) {
            int idx = p * 256 + t;
            int row = idx >> 4, cc = (idx & 15) * 8;
            *(us8*)&((unsigned short*)outp)[(size_t)(m0 + row) * N + n0 + cc] =
                *(const us8*)&Cs[row * 136 + cc];
        }
    }
}

// ---------------- Fused up-projections + gate, DMA-staged -------------------------
// 6 tiles/k-step: A-sem, A-ctx (tdown), B sem_amp/sem_ph/ctx_amp/ctx_ph.
// Tile t lives at gbuf+t*2048, [64][32] bf16, colgroup swizzle pg = g ^ (row&3).
__global__ __launch_bounds__(256) void gate_mfma_kernel(
    const unsigned short* __restrict__ tdown,
    const unsigned short* __restrict__ WsuT,
    const unsigned short* __restrict__ WcuT,
    const void* __restrict__ tempraw,
    void* __restrict__ dout,
    unsigned short* __restrict__ gateb,
    const int* __restrict__ flag)
{
    __shared__ unsigned short gbuf[17408];      // staging 12288; epilogue 17408
    int f = blockIdx.y * gridDim.x + blockIdx.x;
    int rps = gridDim.y >> 3;
    int strip = f & 7, within = f >> 3;
    int by = strip * rps + (within % rps);
    int bx = within / rps;
    int m0 = by * 64, c0 = bx * 64;

    int t = threadIdx.x;
    int lane = t & 63, wave = t >> 6, quad = lane >> 4, l16 = lane & 15;
    int xg = l16 & 3;

    // staging addresses: wave stages quarter `wave` (rows wave*16..+15) of all 6 tiles
    int r_t = wave * 16 + (lane >> 2);
    int g_t = (lane & 3) ^ ((lane >> 2) & 3);
    const unsigned short* s0 = tdown + (size_t)(m0 + r_t) * 256 + g_t * 8;
    const unsigned short* s1 = s0 + 128;
    const unsigned short* s2 = WsuT + (size_t)(c0 + r_t) * 128 + g_t * 8;
    const unsigned short* s3 = WsuT + (size_t)(768 + c0 + r_t) * 128 + g_t * 8;
    const unsigned short* s4 = WcuT + (size_t)(c0 + r_t) * 128 + g_t * 8;
    const unsigned short* s5 = WcuT + (size_t)(768 + c0 + r_t) * 128 + g_t * 8;
    unsigned short* ldq = gbuf + wave * 512;

    f32x4 acc[4][4];
    #pragma unroll
    for (int i = 0; i < 4; i++)
        #pragma unroll
        for (int j = 0; j < 4; j++) acc[i][j] = (f32x4){0.f, 0.f, 0.f, 0.f};

    int Atile = wave >> 1, Btile = 2 + wave;
    for (int k0 = 0; k0 < 128; k0 += 32) {
        __syncthreads();
        dma16(s0 + k0, ldq + 0 * 2048);
        dma16(s1 + k0, ldq + 1 * 2048);
        dma16(s2 + k0, ldq + 2 * 2048);
        dma16(s3 + k0, ldq + 3 * 2048);
        dma16(s4 + k0, ldq + 4 * 2048);
        dma16(s5 + k0, ldq + 5 * 2048);
        __syncthreads();
        bf16x8 af[4], bfr[4];
        #pragma unroll
        for (int i = 0; i < 4; i++)
            af[i] = *(const bf16x8*)&gbuf[Atile * 2048 + (i * 16 + l16) * 32 + ((quad ^ xg) * 8)];
        #pragma unroll
        for (int j = 0; j < 4; j++)
            bfr[j] = *(const bf16x8*)&gbuf[Btile * 2048 + (j * 16 + l16) * 32 + ((quad ^ xg) * 8)];
        #pragma unroll
        for (int i = 0; i < 4; i++)
            #pragma unroll
            for (int j = 0; j < 4; j++)
                acc[i][j] = __builtin_amdgcn_mfma_f32_16x16x32_bf16(af[i], bfr[j], acc[i][j], 0, 0, 0);
    }
    __syncthreads();
    // deposit product tiles (bf16) for exchange
    #pragma unroll
    for (int i = 0; i < 4; i++)
        #pragma unroll
        for (int j = 0; j < 4; j++)
            #pragma unroll
            for (int r = 0; r < 4; r++)
                gbuf[wave * 4352 + (i * 16 + quad * 4 + r) * 68 + j * 16 + l16] = f2bf(acc[i][j][r]);
    __syncthreads();
    int fl = flag[0];
    float tempv = fl ? ((const float*)tempraw)[0] : bf2f(((const unsigned short*)tempraw)[0]);
    #pragma unroll
    for (int p = 0; p < 16; p++) {
        int idx = p * 256 + t;
        int row = idx >> 6, col = idx & 63;
        float sa = softplusf(bf2f(gbuf[0 * 4352 + row * 68 + col]));
        float sp = tanhf(bf2f(gbuf[1 * 4352 + row * 68 + col])) * PI_F;
        float ca = softplusf(bf2f(gbuf[2 * 4352 + row * 68 + col]));
        float cp = tanhf(bf2f(gbuf[3 * 4352 + row * 68 + col])) * PI_F;
        float inter = sa * ca * cosf(sp - cp) * tempv;
        float g = 1.f / (1.f + expf(-inter));
        size_t off = (size_t)GOFF + (size_t)(m0 + row) * D_ + c0 + col;
        unsigned short gb = f2bf(g);
        if (fl) ((float*)dout)[off] = g;
        else    ((unsigned short*)dout)[off] = gb;
        gateb[(size_t)(m0 + row) * D_ + c0 + col] = gb;
    }
}

// ---------------- Pass A (MFMA): raw per-chunk S_c = K^T . V_ext ------------------
__global__ __launch_bounds__(256) void chunk_sum_mfma_kernel(
    const unsigned short* __restrict__ qkvt,
    float* __restrict__ Msum, float* __restrict__ Zsum)
{
    __shared__ __align__(16) unsigned short KT[64 * 136];
    __shared__ __align__(16) unsigned short VT[80 * 136];
    int blk = blockIdx.x;
    int bh = blk / NC, cc = blk - bh * NC;
    int b = bh / H_, h = bh - b * H_;
    int t = threadIdx.x;
    int lane = t & 63, wave = t >> 6, quad = lane >> 4, l16 = lane & 15;
    int lr = t >> 1, lc = (t & 1) * 32;
    size_t rowbase = (size_t)(b * L_ + cc * CHUNK);
    const unsigned short* kg = qkvt + rowbase * 2304 + D_ + h * 64;
    const unsigned short* vg = qkvt + rowbase * 2304 + 2 * D_ + h * 64;
    #pragma unroll
    for (int c = 0; c < 4; c++) {
        us8 kv = *(const us8*)&kg[(size_t)lr * 2304 + lc + c * 8];
        us8 vv = *(const us8*)&vg[(size_t)lr * 2304 + lc + c * 8];
        #pragma unroll
        for (int ii = 0; ii < 8; ii++) {
            KT[(lc + c * 8 + ii) * 136 + lr] = kv[ii];
            VT[(lc + c * 8 + ii) * 136 + lr] = vv[ii];
        }
    }
    if (t < 128) VT[64 * 136 + t] = 0x3F80;   // ones row (bf16 1.0)
    __syncthreads();

    f32x4 acc[5];
    #pragma unroll
    for (int j = 0; j < 5; j++) acc[j] = (f32x4){0.f, 0.f, 0.f, 0.f};
    #pragma unroll
    for (int ks = 0; ks < 4; ks++) {
        bf16x8 a = *(const bf16x8*)&KT[(wave * 16 + l16) * 136 + ks * 32 + quad * 8];
        #pragma unroll
        for (int j = 0; j < 5; j++) {
            bf16x8 bv = *(const bf16x8*)&VT[(j * 16 + l16) * 136 + ks * 32 + quad * 8];
            acc[j] = __builtin_amdgcn_mfma_f32_16x16x32_bf16(a, bv, acc[j], 0, 0, 0);
        }
    }
    float* mo = Msum + (size_t)blk * 4096;
    #pragma unroll
    for (int j = 0; j < 4; j++)
        #pragma unroll
        for (int r = 0; r < 4; r++)
            mo[(wave * 16 + quad * 4 + r) * 64 + j * 16 + l16] = acc[j][r];
    if (l16 == 0) {
        #pragma unroll
        for (int r = 0; r < 4; r++)
            Zsum[(size_t)blk * 64 + wave * 16 + quad * 4 + r] = acc[4][r];
    }
}

// ---------------- Pass C (MFMA): inlined prefix + O = Q.S + tril(QK^T).V ----------
// LDS: Qs[128][64]@0 (DMA, swizzled), Ks@8192; Ps overlays [0,17408); VT@17408
// (80*136); Ss@28288 (80*72). Cout overlays Ps.
__global__ __launch_bounds__(256) void chunk_scan_mfma_kernel(
    const unsigned short* __restrict__ qkvt,
    const float* __restrict__ Msum, const float* __restrict__ Zsum,
    unsigned short* __restrict__ attnb)
{
    __shared__ __align__(16) unsigned short sbuf[34048];
    unsigned short* Qs = sbuf;                  // [128][64] swizzled
    unsigned short* Ks = sbuf + 8192;           // [128][64] swizzled
    unsigned short* Ps = sbuf;                  // [128][136]
    unsigned short* VT = sbuf + 17408;          // [80][136]
    unsigned short* Ss = sbuf + 28288;          // [80][72]
    unsigned short* Cout = sbuf;                // [128][136]

    int blk = blockIdx.x;
    int bh = blk / NC, cc = blk - bh * NC;
    int b = bh / H_, h = bh - b * H_;
    int t = threadIdx.x;
    int lane = t & 63, wave = t >> 6, quad = lane >> 4, l16 = lane & 15;
    int wm = wave * 32;
    int xr = l16 & 7;
    size_t rowbase = (size_t)(b * L_ + cc * CHUNK);
    const unsigned short* qg = qkvt + rowbase * 2304 + h * 64;
    const unsigned short* kg = qkvt + rowbase * 2304 + D_ + h * 64;
    const unsigned short* vg = qkvt + rowbase * 2304 + 2 * D_ + h * 64;

    // ---- DMA-stage Q,K (swizzled [128][64]) ----
    int r8 = lane >> 3, g8 = (lane & 7) ^ r8;
    #pragma unroll
    for (int s = 0; s < 8; s++) {
        int op = s * 4 + wave;                  // 0..31
        int tl = op >> 4, o16 = op & 15;
        const unsigned short* src = (tl ? kg : qg) + (size_t)(o16 * 8 + r8) * 2304 + g8 * 8;
        unsigned short* dst = (tl ? Ks : Qs) + o16 * 512;
        dma16(src, dst);
    }
    // ---- V transpose (scalar) ----
    {
        int lr = t >> 1, lc = (t & 1) * 32;
        #pragma unroll
        for (int c = 0; c < 4; c++) {
            us8 vv = *(const us8*)&vg[(size_t)lr * 2304 + lc + c * 8];
            #pragma unroll
            for (int ii = 0; ii < 8; ii++)
                VT[(lc + c * 8 + ii) * 136 + lr] = vv[ii];
        }
    }
    if (t < 128) VT[64 * 136 + t] = 0x3F80;     // ones row
    // ---- inlined exclusive prefix over chunks (fp32, same order as before) ----
    {
        int d = t & 63, jb = (t >> 6) * 16;
        float a16[16];
        #pragma unroll
        for (int j = 0; j < 16; j++) a16[j] = 0.f;
        for (int c = 0; c < cc; c++) {
            const float* mp = Msum + ((size_t)bh * NC + c) * 4096 + d * 64 + jb;
            #pragma unroll
            for (int g4 = 0; g4 < 4; g4++) {
                float4 sv = *(const float4*)&mp[g4 * 4];
                a16[g4 * 4 + 0] += sv.x; a16[g4 * 4 + 1] += sv.y;
                a16[g4 * 4 + 2] += sv.z; a16[g4 * 4 + 3] += sv.w;
            }
        }
        #pragma unroll
        for (int j = 0; j < 16; j++) Ss[(jb + j) * 72 + d] = f2bf(a16[j]);
    }
    if (t < 64) {
        float rz = 0.f;
        for (int c = 0; c < cc; c++) rz += Zsum[((size_t)bh * NC + c) * 64 + t];
        Ss[64 * 72 + t] = f2bf(rz);
    }
    __syncthreads();

    f32x4 Pacc[2][8], Oacc[2][5];
    #pragma unroll
    for (int i = 0; i < 2; i++) {
        #pragma unroll
        for (int n = 0; n < 8; n++) Pacc[i][n] = (f32x4){0.f, 0.f, 0.f, 0.f};
        #pragma unroll
        for (int j = 0; j < 5; j++) Oacc[i][j] = (f32x4){0.f, 0.f, 0.f, 0.f};
    }
    bf16x8 aq[2][2];
    #pragma unroll
    for (int i = 0; i < 2; i++)
        #pragma unroll
        for (int ks = 0; ks < 2; ks++)
            aq[i][ks] = *(const bf16x8*)&Qs[(wm + i * 16 + l16) * 64 + (((ks * 4 + quad) ^ xr) * 8)];
    #pragma unroll
    for (int n = 0; n < 8; n++)
        #pragma unroll
        for (int ks = 0; ks < 2; ks++) {
            bf16x8 bk = *(const bf16x8*)&Ks[(n * 16 + l16) * 64 + (((ks * 4 + quad) ^ xr) * 8)];
            #pragma unroll
            for (int i = 0; i < 2; i++)
                Pacc[i][n] = __builtin_amdgcn_mfma_f32_16x16x32_bf16(aq[i][ks], bk, Pacc[i][n], 0, 0, 0);
        }
    #pragma unroll
    for (int j = 0; j < 5; j++)
        #pragma unroll
        for (int ks = 0; ks < 2; ks++) {
            bf16x8 bs = *(const bf16x8*)&Ss[(j * 16 + l16) * 72 + ks * 32 + quad * 8];
            #pragma unroll
            for (int i = 0; i < 2; i++)
                Oacc[i][j] = __builtin_amdgcn_mfma_f32_16x16x32_bf16(aq[i][ks], bs, Oacc[i][j], 0, 0, 0);
        }
    __syncthreads();   // Q,K,S reads done — overlay P

    #pragma unroll
    for (int i = 0; i < 2; i++)
        #pragma unroll
        for (int n = 0; n < 8; n++)
            #pragma unroll
            for (int r = 0; r < 4; r++) {
                int trow = wm + i * 16 + quad * 4 + r;
                int scol = n * 16 + l16;
                Ps[trow * 136 + scol] = (scol <= trow) ? f2bf(Pacc[i][n][r]) : 0;
            }
    __syncthreads();

    #pragma unroll
    for (int ks = 0; ks < 4; ks++) {
        bf16x8 ap[2];
        #pragma unroll
        for (int i = 0; i < 2; i++)
            ap[i] = *(const bf16x8*)&Ps[(wm + i * 16 + l16) * 136 + ks * 32 + quad * 8];
        #pragma unroll
        for (int j = 0; j < 5; j++) {
            bf16x8 bv = *(const bf16x8*)&VT[(j * 16 + l16) * 136 + ks * 32 + quad * 8];
            #pragma unroll
            for (int i = 0; i < 2; i++)
                Oacc[i][j] = __builtin_amdgcn_mfma_f32_16x16x32_bf16(ap[i], bv, Oacc[i][j], 0, 0, 0);
        }
    }
    __syncthreads();   // P reads done — overlay Cout

    #pragma unroll
    for (int i = 0; i < 2; i++) {
        #pragma unroll
        for (int r = 0; r < 4; r++) {
            float den = __shfl(Oacc[i][4][r], lane & 48) + 1e-6f;
            float inv = 1.f / den;
            #pragma unroll
            for (int j = 0; j < 4; j++)
                Cout[(wm + i * 16 + quad * 4 + r) * 136 + j * 16 + l16] = f2bf(Oacc[i][j][r] * inv);
        }
    }
    __syncthreads();
    unsigned short* abase = attnb + rowbase * D_ + h * 64;
    #pragma unroll
    for (int p = 0; p < 4; p++) {
        int idx = p * 256 + t;
        int row = idx >> 3, cg = (idx & 7) * 8;
        *(us8*)&abase[(size_t)row * D_ + cg] = *(const us8*)&Cout[row * 136 + cg];
    }
}

extern "C" void kernel_launch(void* const* d_in, const int* in_sizes, int n_in,
                              void* d_out, int out_size, void* d_ws, size_t ws_size,
                              hipStream_t stream)
{
    char* w = (char*)d_ws;
    auto alloc = [&](size_t bytes) { void* p = (void*)w; w += (bytes + 255) & ~(size_t)255; return p; };
    int*            flagp   = (int*)alloc(256);
    unsigned short* x_c     = (unsigned short*)alloc((size_t)BL * D_ * 2);   // reused as attnb
    unsigned short* attnb   = x_c;
    unsigned short* xn      = (unsigned short*)alloc((size_t)BL * D_ * 2);
    unsigned short* WqkvT   = (unsigned short*)alloc((size_t)2304 * 768 * 2);
    unsigned short* WdT     = (unsigned short*)alloc((size_t)256 * 768 * 2);
    unsigned short* WsuT    = (unsigned short*)alloc((size_t)1536 * 128 * 2);
    unsigned short* WcuT    = (unsigned short*)alloc((size_t)1536 * 128 * 2);
    unsigned short* WprojT  = (unsigned short*)alloc((size_t)768 * 768 * 2);
    unsigned short* bqkv_c  = (unsigned short*)alloc((size_t)2304 * 2);
    unsigned short* bproj_c = (unsigned short*)alloc((size_t)768 * 2);
    unsigned short* tdown   = (unsigned short*)alloc((size_t)BL * 256 * 2);
    float*          Zsum    = (float*)alloc((size_t)BH * NC * 64 * 4);
    unsigned short* qkvt    = (unsigned short*)alloc((size_t)BL * 2304 * 2);
    float*          Msum    = (float*)alloc((size_t)BH * NC * 4096 * 4);
    // gateb aliases Msum: gate writes @t3, qkv reads @t4; Msum written @t5.
    unsigned short* gateb   = (unsigned short*)Msum;

    dim3 blk(256);
    // 0. detect + weight prep (transposes + bias converts)
    detect_kernel<<<1, blk, 0, stream>>>((const unsigned short*)d_in[0], flagp);
    prep_mega_kernel<<<2892, blk, 0, stream>>>(
        d_in[1], WqkvT, d_in[3], WdT, d_in[4], WsuT,
        d_in[5], d_in[6], WcuT, d_in[8], WprojT,
        d_in[2], bqkv_c, d_in[9], bproj_c, flagp);
    // 1. fused convert + LayerNorm (gamma/beta raw)
    conv_ln_kernel<<<BL, blk, 0, stream>>>(d_in[0], d_in[10], d_in[11], x_c, xn, flagp);
    // 2. merged down-projections (silu)
    mfma_gemm_kernel<1><<<dim3(2, 32), blk, 0, stream>>>(x_c, 768, WdT, nullptr, nullptr, tdown, flagp, 256, 768);
    // 3. fused up-projections + gate -> d_out gate region + bf16 shadow
    gate_mfma_kernel<<<dim3(12, 64), blk, 0, stream>>>(tdown, WsuT, WcuT, d_in[7], d_out, gateb, flagp);
    // 4. qkv GEMM with fused elu/gate epilogue
    mfma_gemm_kernel<2><<<dim3(18, 32), blk, 0, stream>>>(xn, 768, WqkvT, bqkv_c, gateb, qkvt, flagp, 2304, 768);
    // 5. chunked causal linear attention (prefix inlined in scan)
    chunk_sum_mfma_kernel<<<BH * NC, blk, 0, stream>>>(qkvt, Msum, Zsum);
    chunk_scan_mfma_kernel<<<BH * NC, blk, 0, stream>>>(qkvt, Msum, Zsum, attnb);
    // 6. output projection (flagged store)
    mfma_gemm_kernel<3><<<dim3(6, 32), blk, 0, stream>>>(attnb, 768, WprojT, bproj_c, nullptr, d_out, flagp, 768, 768);
}

// Round 9
// 225.159 us; speedup vs baseline: 1.1225x; 1.1225x over previous
//
#include <hip/hip_runtime.h>

#define B_    2
#define L_    2048
#define D_    768
#define H_    12
#define BL    4096      // B_*L_
#define BH    24        // B_*H_
#define CHUNK 128
#define NC    16        // L_/CHUNK
#define GOFF  3145728   // element offset of gate output within d_out
#define PI_F  3.14159265358979f

typedef __bf16 bf16x8 __attribute__((ext_vector_type(8)));
typedef float  f32x4  __attribute__((ext_vector_type(4)));
typedef unsigned short us8 __attribute__((ext_vector_type(8)));

__device__ __forceinline__ float bf2f(unsigned short u) {
    return __uint_as_float(((unsigned int)u) << 16);
}
__device__ __forceinline__ unsigned short f2bf(float f) {
    unsigned int u = __float_as_uint(f);
    unsigned int r = (u + 0x7fffu + ((u >> 16) & 1u)) >> 16;
    return (unsigned short)r;
}
// fast transcendentals: hardware v_exp/v_log/v_cos/v_rcp paths
__device__ __forceinline__ float rcp_fast(float x) { return __builtin_amdgcn_rcpf(x); }
__device__ __forceinline__ float softplus_fast(float x) {
    return x > 20.f ? x : __logf(1.f + __expf(x));
}
__device__ __forceinline__ float tanh_fast(float x) {
    float e2 = __expf(2.f * x);               // inf for large x -> rcp -> 0 -> 1 (safe)
    return 1.f - 2.f * rcp_fast(e2 + 1.f);
}
// async global->LDS, 16B per lane; LDS dest = wave-uniform base + lane*16
__device__ __forceinline__ void dma16(const unsigned short* g, unsigned short* l) {
    __builtin_amdgcn_global_load_lds(
        (const __attribute__((address_space(1))) unsigned int*)g,
        (__attribute__((address_space(3))) unsigned int*)l, 16, 0, 0);
}

// ---------------- dtype detector ----------------
__global__ __launch_bounds__(256) void detect_kernel(const unsigned short* __restrict__ x,
                                                     int* __restrict__ flag)
{
    __shared__ int cnt;
    if (threadIdx.x == 0) cnt = 0;
    __syncthreads();
    int c = 0;
    #pragma unroll
    for (int i = 0; i < 16; i++) {
        unsigned short u = x[threadIdx.x * 16 + i];
        int e = (u >> 7) & 0xff;
        if (e < 100 || e > 140) c++;
    }
    atomicAdd(&cnt, c);
    __syncthreads();
    if (threadIdx.x == 0) flag[0] = (cnt > 512) ? 1 : 0;   // 1 = inputs are fp32
}

// ---------------- prep: 6 weight transposes + bqkv/bproj converts -----------------
__global__ __launch_bounds__(256) void prep_mega_kernel(
    const void* __restrict__ s0, unsigned short* __restrict__ dq,   // Wqkv 768x2304
    const void* __restrict__ s1, unsigned short* __restrict__ dd,   // Wsd -> WdT[0]
    const void* __restrict__ s2, unsigned short* __restrict__ dsu,  // Wsu 128x1536
    const void* __restrict__ s3,                                    // Wcd -> WdT[128*768]
    const void* __restrict__ s4, unsigned short* __restrict__ dcu,  // Wcu 128x1536
    const void* __restrict__ s5, unsigned short* __restrict__ dp,   // Wproj 768x768
    const void* __restrict__ sbq, unsigned short* __restrict__ dbq, // bqkv 2304
    const void* __restrict__ sbp, unsigned short* __restrict__ dbp, // bproj 768
    const int* __restrict__ flag)
{
    int id = blockIdx.x;
    int fl = flag[0];
    if (id >= 2880) {   // small vector converts
        const void* src; unsigned short* dst; int n, base;
        if (id < 2889) { src = sbq; dst = dbq; n = 2304; base = (id - 2880) * 256; }
        else           { src = sbp; dst = dbp; n = 768;  base = (id - 2889) * 256; }
        int i = base + threadIdx.x;
        if (i < n) dst[i] = fl ? f2bf(((const float*)src)[i]) : ((const unsigned short*)src)[i];
        return;
    }
    __shared__ unsigned short tile[32][33];
    const void* src; unsigned short* dst; int K, N, tid;
    if (id < 1728)      { src = s0; dst = dq;  K = 768; N = 2304; tid = id; }
    else if (id < 1824) { src = s1; dst = dd;  K = 768; N = 128;  tid = id - 1728; }
    else if (id < 2016) { src = s2; dst = dsu; K = 128; N = 1536; tid = id - 1824; }
    else if (id < 2112) { src = s3; dst = dd + (size_t)128 * 768; K = 768; N = 128; tid = id - 2016; }
    else if (id < 2304) { src = s4; dst = dcu; K = 128; N = 1536; tid = id - 2112; }
    else                { src = s5; dst = dp;  K = 768; N = 768;  tid = id - 2304; }
    int tn = N / 32;
    int by = (tid / tn) * 32, bx = (tid % tn) * 32;
    int tx = threadIdx.x & 31, tyb = threadIdx.x >> 5;
    #pragma unroll
    for (int i = 0; i < 4; i++) {
        int k = by + tyb * 4 + i, n = bx + tx;
        size_t off = (size_t)k * N + n;
        tile[tyb * 4 + i][tx] = fl ? f2bf(((const float*)src)[off]) : ((const unsigned short*)src)[off];
    }
    __syncthreads();
    #pragma unroll
    for (int i = 0; i < 4; i++) {
        int n = bx + tyb * 4 + i, k = by + tx;
        dst[(size_t)n * K + k] = tile[tx][tyb * 4 + i];
    }
}

// ---------------- Fused convert + LayerNorm (gamma/beta read raw) -----------------
__global__ __launch_bounds__(256) void conv_ln_kernel(
    const void* __restrict__ xin,
    const void* __restrict__ gr, const void* __restrict__ br,
    unsigned short* __restrict__ x_c,
    unsigned short* __restrict__ xn,
    const int* __restrict__ flag)
{
    int row = blockIdx.x, t = threadIdx.x;
    int fl = flag[0];
    float v[3];
    #pragma unroll
    for (int j = 0; j < 3; j++) {
        int c = t + j * 256;
        v[j] = fl ? ((const float*)xin)[(size_t)row * D_ + c]
                  : bf2f(((const unsigned short*)xin)[(size_t)row * D_ + c]);
    }
    __shared__ float red[8];
    float s = v[0] + v[1] + v[2];
    #pragma unroll
    for (int m = 32; m >= 1; m >>= 1) s += __shfl_xor(s, m, 64);
    int wid = t >> 6;
    if ((t & 63) == 0) red[wid] = s;
    __syncthreads();
    float mean = (red[0] + red[1] + red[2] + red[3]) * (1.f / 768.f);
    float s2 = 0.f;
    #pragma unroll
    for (int j = 0; j < 3; j++) { float d = v[j] - mean; s2 += d * d; }
    #pragma unroll
    for (int m = 32; m >= 1; m >>= 1) s2 += __shfl_xor(s2, m, 64);
    if ((t & 63) == 0) red[4 + wid] = s2;
    __syncthreads();
    float var = (red[4] + red[5] + red[6] + red[7]) * (1.f / 768.f);
    float rs = rsqrtf(var + 1e-5f);
    #pragma unroll
    for (int j = 0; j < 3; j++) {
        int c = t + j * 256;
        float gv = fl ? ((const float*)gr)[c] : bf2f(((const unsigned short*)gr)[c]);
        float bv = fl ? ((const float*)br)[c] : bf2f(((const unsigned short*)br)[c]);
        x_c[(size_t)row * D_ + c] = f2bf(v[j]);
        float o = (v[j] - mean) * rs * gv + bv;
        xn[(size_t)row * D_ + c] = f2bf(o);
    }
}

// ---------------- MFMA GEMM v3 (DMA staging + swizzle; fast-math epilogues) -------
template<int EPI>
__global__ __launch_bounds__(256) void mfma_gemm_kernel(
    const unsigned short* __restrict__ A, int lda,
    const unsigned short* __restrict__ BT,
    const unsigned short* __restrict__ bias,
    const unsigned short* __restrict__ gateb,
    void* __restrict__ outp,
    const int* __restrict__ flag,
    int N, int K)
{
    __shared__ unsigned short sbuf[17408];
    unsigned short* As = sbuf;
    unsigned short* Bs = sbuf + 8192;
    unsigned short* Cs = sbuf;

    int f = blockIdx.y * gridDim.x + blockIdx.x;
    int rps = gridDim.y >> 3;
    int strip = f & 7, within = f >> 3;
    int by = strip * rps + (within % rps);
    int bx = within / rps;
    int m0 = by * 128, n0 = bx * 128;

    int t = threadIdx.x;
    int lane = t & 63, wave = t >> 6, quad = lane >> 4, l16 = lane & 15;
    int wm = (wave & 1) * 64, wn = (wave >> 1) * 64;
    int xr = l16 & 7;

    int sr8 = lane >> 3;
    int scg = (lane & 7) ^ sr8;
    const unsigned short* ApL = A  + (size_t)(m0 + wave * 32 + sr8) * lda + scg * 8;
    const unsigned short* BpL = BT + (size_t)(n0 + wave * 32 + sr8) * K   + scg * 8;
    unsigned short* AsW = As + wave * 32 * 64;
    unsigned short* BsW = Bs + wave * 32 * 64;

    f32x4 acc[4][4];
    #pragma unroll
    for (int i = 0; i < 4; i++)
        #pragma unroll
        for (int j = 0; j < 4; j++) acc[i][j] = (f32x4){0.f, 0.f, 0.f, 0.f};

    for (int k0 = 0; k0 < K; k0 += 64) {
        __syncthreads();
        #pragma unroll
        for (int c = 0; c < 4; c++) {
            dma16(ApL + (size_t)(c * 8) * lda + k0, AsW + c * 512);
            dma16(BpL + (size_t)(c * 8) * K   + k0, BsW + c * 512);
        }
        __syncthreads();
        #pragma unroll
        for (int ks = 0; ks < 2; ks++) {
            bf16x8 af[4], bfr[4];
            #pragma unroll
            for (int i = 0; i < 4; i++)
                af[i] = *(const bf16x8*)&As[(wm + i * 16 + l16) * 64 + (((ks * 4 + quad) ^ xr) * 8)];
            #pragma unroll
            for (int j = 0; j < 4; j++)
                bfr[j] = *(const bf16x8*)&Bs[(wn + j * 16 + l16) * 64 + (((ks * 4 + quad) ^ xr) * 8)];
            #pragma unroll
            for (int i = 0; i < 4; i++)
                #pragma unroll
                for (int j = 0; j < 4; j++)
                    acc[i][j] = __builtin_amdgcn_mfma_f32_16x16x32_bf16(af[i], bfr[j], acc[i][j], 0, 0, 0);
        }
    }

    int fl = (EPI == 3) ? flag[0] : 0;
    __syncthreads();
    #pragma unroll
    for (int j = 0; j < 4; j++) {
        int col = n0 + wn + j * 16 + l16;
        float bv = bias ? bf2f(bias[col]) : 0.f;
        #pragma unroll
        for (int i = 0; i < 4; i++) {
            #pragma unroll
            for (int r = 0; r < 4; r++) {
                int row = m0 + wm + i * 16 + quad * 4 + r;
                float v = acc[i][j][r] + bv;
                if (EPI == 1) v = v * rcp_fast(1.f + __expf(-v));     // silu
                if (EPI == 2) {
                    if (col < D_) {
                        v = v > 0.f ? v + 1.f : __expf(v);             // elu+1
                    } else if (col < 2 * D_) {
                        float gg = bf2f(gateb[(size_t)row * D_ + (col - D_)]);
                        v *= (1.f + gg);
                        v = v > 0.f ? v + 1.f : __expf(v);
                    }
                }
                if (EPI == 3 && fl) {
                    ((float*)outp)[(size_t)row * N + col] = v;
                } else {
                    Cs[(wm + i * 16 + quad * 4 + r) * 136 + wn + j * 16 + l16] = f2bf(v);
                }
            }
        }
    }
    if (!(EPI == 3 && fl)) {
        __syncthreads();
        #pragma unroll
        for (int p = 0; p < 8; p++) {
            int idx = p * 256 + t;
            int row = idx >> 4, cc = (idx & 15) * 8;
            *(us8*)&((unsigned short*)outp)[(size_t)(m0 + row) * N + n0 + cc] =
                *(const us8*)&Cs[row * 136 + cc];
        }
    }
}

// ---------------- Fused up-projections + gate, DMA-staged, fast transcendentals ---
__global__ __launch_bounds__(256) void gate_mfma_kernel(
    const unsigned short* __restrict__ tdown,
    const unsigned short* __restrict__ WsuT,
    const unsigned short* __restrict__ WcuT,
    const void* __restrict__ tempraw,
    void* __restrict__ dout,
    unsigned short* __restrict__ gateb,
    const int* __restrict__ flag)
{
    __shared__ unsigned short gbuf[17408];
    int f = blockIdx.y * gridDim.x + blockIdx.x;
    int rps = gridDim.y >> 3;
    int strip = f & 7, within = f >> 3;
    int by = strip * rps + (within % rps);
    int bx = within / rps;
    int m0 = by * 64, c0 = bx * 64;

    int t = threadIdx.x;
    int lane = t & 63, wave = t >> 6, quad = lane >> 4, l16 = lane & 15;
    int xg = l16 & 3;

    int r_t = wave * 16 + (lane >> 2);
    int g_t = (lane & 3) ^ ((lane >> 2) & 3);
    const unsigned short* s0 = tdown + (size_t)(m0 + r_t) * 256 + g_t * 8;
    const unsigned short* s1 = s0 + 128;
    const unsigned short* s2 = WsuT + (size_t)(c0 + r_t) * 128 + g_t * 8;
    const unsigned short* s3 = WsuT + (size_t)(768 + c0 + r_t) * 128 + g_t * 8;
    const unsigned short* s4 = WcuT + (size_t)(c0 + r_t) * 128 + g_t * 8;
    const unsigned short* s5 = WcuT + (size_t)(768 + c0 + r_t) * 128 + g_t * 8;
    unsigned short* ldq = gbuf + wave * 512;

    f32x4 acc[4][4];
    #pragma unroll
    for (int i = 0; i < 4; i++)
        #pragma unroll
        for (int j = 0; j < 4; j++) acc[i][j] = (f32x4){0.f, 0.f, 0.f, 0.f};

    int Atile = wave >> 1, Btile = 2 + wave;
    for (int k0 = 0; k0 < 128; k0 += 32) {
        __syncthreads();
        dma16(s0 + k0, ldq + 0 * 2048);
        dma16(s1 + k0, ldq + 1 * 2048);
        dma16(s2 + k0, ldq + 2 * 2048);
        dma16(s3 + k0, ldq + 3 * 2048);
        dma16(s4 + k0, ldq + 4 * 2048);
        dma16(s5 + k0, ldq + 5 * 2048);
        __syncthreads();
        bf16x8 af[4], bfr[4];
        #pragma unroll
        for (int i = 0; i < 4; i++)
            af[i] = *(const bf16x8*)&gbuf[Atile * 2048 + (i * 16 + l16) * 32 + ((quad ^ xg) * 8)];
        #pragma unroll
        for (int j = 0; j < 4; j++)
            bfr[j] = *(const bf16x8*)&gbuf[Btile * 2048 + (j * 16 + l16) * 32 + ((quad ^ xg) * 8)];
        #pragma unroll
        for (int i = 0; i < 4; i++)
            #pragma unroll
            for (int j = 0; j < 4; j++)
                acc[i][j] = __builtin_amdgcn_mfma_f32_16x16x32_bf16(af[i], bfr[j], acc[i][j], 0, 0, 0);
    }
    __syncthreads();
    #pragma unroll
    for (int i = 0; i < 4; i++)
        #pragma unroll
        for (int j = 0; j < 4; j++)
            #pragma unroll
            for (int r = 0; r < 4; r++)
                gbuf[wave * 4352 + (i * 16 + quad * 4 + r) * 68 + j * 16 + l16] = f2bf(acc[i][j][r]);
    __syncthreads();
    int fl = flag[0];
    float tempv = fl ? ((const float*)tempraw)[0] : bf2f(((const unsigned short*)tempraw)[0]);
    #pragma unroll
    for (int p = 0; p < 16; p++) {
        int idx = p * 256 + t;
        int row = idx >> 6, col = idx & 63;
        float sa = softplus_fast(bf2f(gbuf[0 * 4352 + row * 68 + col]));
        float sp = tanh_fast(bf2f(gbuf[1 * 4352 + row * 68 + col]));
        float ca = softplus_fast(bf2f(gbuf[2 * 4352 + row * 68 + col]));
        float cp = tanh_fast(bf2f(gbuf[3 * 4352 + row * 68 + col]));
        float inter = sa * ca * __cosf(PI_F * (sp - cp)) * tempv;
        float g = rcp_fast(1.f + __expf(-inter));
        size_t off = (size_t)GOFF + (size_t)(m0 + row) * D_ + c0 + col;
        unsigned short gb = f2bf(g);
        if (fl) ((float*)dout)[off] = g;
        else    ((unsigned short*)dout)[off] = gb;
        gateb[(size_t)(m0 + row) * D_ + c0 + col] = gb;
    }
}

// ---------------- Pass A (MFMA): raw per-chunk S_c = K^T . V_ext ------------------
__global__ __launch_bounds__(256) void chunk_sum_mfma_kernel(
    const unsigned short* __restrict__ qkvt,
    float* __restrict__ Msum, float* __restrict__ Zsum)
{
    __shared__ __align__(16) unsigned short KT[64 * 136];
    __shared__ __align__(16) unsigned short VT[80 * 136];
    int blk = blockIdx.x;
    int bh = blk / NC, cc = blk - bh * NC;
    int b = bh / H_, h = bh - b * H_;
    int t = threadIdx.x;
    int lane = t & 63, wave = t >> 6, quad = lane >> 4, l16 = lane & 15;
    int lr = t >> 1, lc = (t & 1) * 32;
    size_t rowbase = (size_t)(b * L_ + cc * CHUNK);
    const unsigned short* kg = qkvt + rowbase * 2304 + D_ + h * 64;
    const unsigned short* vg = qkvt + rowbase * 2304 + 2 * D_ + h * 64;
    #pragma unroll
    for (int c = 0; c < 4; c++) {
        us8 kv = *(const us8*)&kg[(size_t)lr * 2304 + lc + c * 8];
        us8 vv = *(const us8*)&vg[(size_t)lr * 2304 + lc + c * 8];
        #pragma unroll
        for (int ii = 0; ii < 8; ii++) {
            KT[(lc + c * 8 + ii) * 136 + lr] = kv[ii];
            VT[(lc + c * 8 + ii) * 136 + lr] = vv[ii];
        }
    }
    if (t < 128) VT[64 * 136 + t] = 0x3F80;   // ones row (bf16 1.0)
    __syncthreads();

    f32x4 acc[5];
    #pragma unroll
    for (int j = 0; j < 5; j++) acc[j] = (f32x4){0.f, 0.f, 0.f, 0.f};
    #pragma unroll
    for (int ks = 0; ks < 4; ks++) {
        bf16x8 a = *(const bf16x8*)&KT[(wave * 16 + l16) * 136 + ks * 32 + quad * 8];
        #pragma unroll
        for (int j = 0; j < 5; j++) {
            bf16x8 bv = *(const bf16x8*)&VT[(j * 16 + l16) * 136 + ks * 32 + quad * 8];
            acc[j] = __builtin_amdgcn_mfma_f32_16x16x32_bf16(a, bv, acc[j], 0, 0, 0);
        }
    }
    float* mo = Msum + (size_t)blk * 4096;
    #pragma unroll
    for (int j = 0; j < 4; j++)
        #pragma unroll
        for (int r = 0; r < 4; r++)
            mo[(wave * 16 + quad * 4 + r) * 64 + j * 16 + l16] = acc[j][r];
    if (l16 == 0) {
        #pragma unroll
        for (int r = 0; r < 4; r++)
            Zsum[(size_t)blk * 64 + wave * 16 + quad * 4 + r] = acc[4][r];
    }
}

// ---------------- Pass C (MFMA): inlined prefix + O = Q.S + tril(QK^T).V ----------
// Heavy-prefix blocks (high cc) dispatch first via reversed cc mapping.
__global__ __launch_bounds__(256) void chunk_scan_mfma_kernel(
    const unsigned short* __restrict__ qkvt,
    const float* __restrict__ Msum, const float* __restrict__ Zsum,
    unsigned short* __restrict__ attnb)
{
    __shared__ __align__(16) unsigned short sbuf[34048];
    unsigned short* Qs = sbuf;                  // [128][64] swizzled
    unsigned short* Ks = sbuf + 8192;           // [128][64] swizzled
    unsigned short* Ps = sbuf;                  // [128][136]
    unsigned short* VT = sbuf + 17408;          // [80][136]
    unsigned short* Ss = sbuf + 28288;          // [80][72]
    unsigned short* Cout = sbuf;                // [128][136]

    int blk = blockIdx.x;
    int bh = blk / NC, cc = NC - 1 - (blk - bh * NC);   // heavy blocks first
    int b = bh / H_, h = bh - b * H_;
    int t = threadIdx.x;
    int lane = t & 63, wave = t >> 6, quad = lane >> 4, l16 = lane & 15;
    int wm = wave * 32;
    int xr = l16 & 7;
    size_t rowbase = (size_t)(b * L_ + cc * CHUNK);
    const unsigned short* qg = qkvt + rowbase * 2304 + h * 64;
    const unsigned short* kg = qkvt + rowbase * 2304 + D_ + h * 64;
    const unsigned short* vg = qkvt + rowbase * 2304 + 2 * D_ + h * 64;

    // ---- DMA-stage Q,K (swizzled [128][64]) ----
    int r8 = lane >> 3, g8 = (lane & 7) ^ r8;
    #pragma unroll
    for (int s = 0; s < 8; s++) {
        int op = s * 4 + wave;                  // 0..31
        int tl = op >> 4, o16 = op & 15;
        const unsigned short* src = (tl ? kg : qg) + (size_t)(o16 * 8 + r8) * 2304 + g8 * 8;
        unsigned short* dst = (tl ? Ks : Qs) + o16 * 512;
        dma16(src, dst);
    }
    // ---- V transpose (scalar) ----
    {
        int lr = t >> 1, lc = (t & 1) * 32;
        #pragma unroll
        for (int c = 0; c < 4; c++) {
            us8 vv = *(const us8*)&vg[(size_t)lr * 2304 + lc + c * 8];
            #pragma unroll
            for (int ii = 0; ii < 8; ii++)
                VT[(lc + c * 8 + ii) * 136 + lr] = vv[ii];
        }
    }
    if (t < 128) VT[64 * 136 + t] = 0x3F80;     // ones row
    // ---- inlined exclusive prefix over chunks (fp32) ----
    {
        int d = t & 63, jb = (t >> 6) * 16;
        float a16[16];
        #pragma unroll
        for (int j = 0; j < 16; j++) a16[j] = 0.f;
        for (int c = 0; c < cc; c++) {
            const float* mp = Msum + ((size_t)bh * NC + c) * 4096 + d * 64 + jb;
            #pragma unroll
            for (int g4 = 0; g4 < 4; g4++) {
                float4 sv = *(const float4*)&mp[g4 * 4];
                a16[g4 * 4 + 0] += sv.x; a16[g4 * 4 + 1] += sv.y;
                a16[g4 * 4 + 2] += sv.z; a16[g4 * 4 + 3] += sv.w;
            }
        }
        #pragma unroll
        for (int j = 0; j < 16; j++) Ss[(jb + j) * 72 + d] = f2bf(a16[j]);
    }
    if (t < 64) {
        float rz = 0.f;
        for (int c = 0; c < cc; c++) rz += Zsum[((size_t)bh * NC + c) * 64 + t];
        Ss[64 * 72 + t] = f2bf(rz);
    }
    __syncthreads();

    f32x4 Pacc[2][8], Oacc[2][5];
    #pragma unroll
    for (int i = 0; i < 2; i++) {
        #pragma unroll
        for (int n = 0; n < 8; n++) Pacc[i][n] = (f32x4){0.f, 0.f, 0.f, 0.f};
        #pragma unroll
        for (int j = 0; j < 5; j++) Oacc[i][j] = (f32x4){0.f, 0.f, 0.f, 0.f};
    }
    bf16x8 aq[2][2];
    #pragma unroll
    for (int i = 0; i < 2; i++)
        #pragma unroll
        for (int ks = 0; ks < 2; ks++)
            aq[i][ks] = *(const bf16x8*)&Qs[(wm + i * 16 + l16) * 64 + (((ks * 4 + quad) ^ xr) * 8)];
    #pragma unroll
    for (int n = 0; n < 8; n++)
        #pragma unroll
        for (int ks = 0; ks < 2; ks++) {
            bf16x8 bk = *(const bf16x8*)&Ks[(n * 16 + l16) * 64 + (((ks * 4 + quad) ^ xr) * 8)];
            #pragma unroll
            for (int i = 0; i < 2; i++)
                Pacc[i][n] = __builtin_amdgcn_mfma_f32_16x16x32_bf16(aq[i][ks], bk, Pacc[i][n], 0, 0, 0);
        }
    #pragma unroll
    for (int j = 0; j < 5; j++)
        #pragma unroll
        for (int ks = 0; ks < 2; ks++) {
            bf16x8 bs = *(const bf16x8*)&Ss[(j * 16 + l16) * 72 + ks * 32 + quad * 8];
            #pragma unroll
            for (int i = 0; i < 2; i++)
                Oacc[i][j] = __builtin_amdgcn_mfma_f32_16x16x32_bf16(aq[i][ks], bs, Oacc[i][j], 0, 0, 0);
        }
    __syncthreads();   // Q,K,S reads done — overlay P

    #pragma unroll
    for (int i = 0; i < 2; i++)
        #pragma unroll
        for (int n = 0; n < 8; n++)
            #pragma unroll
            for (int r = 0; r < 4; r++) {
                int trow = wm + i * 16 + quad * 4 + r;
                int scol = n * 16 + l16;
                Ps[trow * 136 + scol] = (scol <= trow) ? f2bf(Pacc[i][n][r]) : 0;
            }
    __syncthreads();

    #pragma unroll
    for (int ks = 0; ks < 4; ks++) {
        bf16x8 ap[2];
        #pragma unroll
        for (int i = 0; i < 2; i++)
            ap[i] = *(const bf16x8*)&Ps[(wm + i * 16 + l16) * 136 + ks * 32 + quad * 8];
        #pragma unroll
        for (int j = 0; j < 5; j++) {
            bf16x8 bv = *(const bf16x8*)&VT[(j * 16 + l16) * 136 + ks * 32 + quad * 8];
            #pragma unroll
            for (int i = 0; i < 2; i++)
                Oacc[i][j] = __builtin_amdgcn_mfma_f32_16x16x32_bf16(ap[i], bv, Oacc[i][j], 0, 0, 0);
        }
    }
    __syncthreads();   // P reads done — overlay Cout

    #pragma unroll
    for (int i = 0; i < 2; i++) {
        #pragma unroll
        for (int r = 0; r < 4; r++) {
            float den = __shfl(Oacc[i][4][r], lane & 48) + 1e-6f;
            float inv = 1.f / den;
            #pragma unroll
            for (int j = 0; j < 4; j++)
                Cout[(wm + i * 16 + quad * 4 + r) * 136 + j * 16 + l16] = f2bf(Oacc[i][j][r] * inv);
        }
    }
    __syncthreads();
    unsigned short* abase = attnb + rowbase * D_ + h * 64;
    #pragma unroll
    for (int p = 0; p < 4; p++) {
        int idx = p * 256 + t;
        int row = idx >> 3, cg = (idx & 7) * 8;
        *(us8*)&abase[(size_t)row * D_ + cg] = *(const us8*)&Cout[row * 136 + cg];
    }
}

extern "C" void kernel_launch(void* const* d_in, const int* in_sizes, int n_in,
                              void* d_out, int out_size, void* d_ws, size_t ws_size,
                              hipStream_t stream)
{
    char* w = (char*)d_ws;
    auto alloc = [&](size_t bytes) { void* p = (void*)w; w += (bytes + 255) & ~(size_t)255; return p; };
    int*            flagp   = (int*)alloc(256);
    unsigned short* x_c     = (unsigned short*)alloc((size_t)BL * D_ * 2);   // reused as attnb
    unsigned short* attnb   = x_c;
    unsigned short* xn      = (unsigned short*)alloc((size_t)BL * D_ * 2);
    unsigned short* WqkvT   = (unsigned short*)alloc((size_t)2304 * 768 * 2);
    unsigned short* WdT     = (unsigned short*)alloc((size_t)256 * 768 * 2);
    unsigned short* WsuT    = (unsigned short*)alloc((size_t)1536 * 128 * 2);
    unsigned short* WcuT    = (unsigned short*)alloc((size_t)1536 * 128 * 2);
    unsigned short* WprojT  = (unsigned short*)alloc((size_t)768 * 768 * 2);
    unsigned short* bqkv_c  = (unsigned short*)alloc((size_t)2304 * 2);
    unsigned short* bproj_c = (unsigned short*)alloc((size_t)768 * 2);
    unsigned short* tdown   = (unsigned short*)alloc((size_t)BL * 256 * 2);
    float*          Zsum    = (float*)alloc((size_t)BH * NC * 64 * 4);
    unsigned short* qkvt    = (unsigned short*)alloc((size_t)BL * 2304 * 2);
    float*          Msum    = (float*)alloc((size_t)BH * NC * 4096 * 4);
    // gateb aliases Msum: gate writes @t3, qkv reads @t4; Msum written @t5.
    unsigned short* gateb   = (unsigned short*)Msum;

    dim3 blk(256);
    // 0. detect + weight prep (transposes + bias converts)
    detect_kernel<<<1, blk, 0, stream>>>((const unsigned short*)d_in[0], flagp);
    prep_mega_kernel<<<2892, blk, 0, stream>>>(
        d_in[1], WqkvT, d_in[3], WdT, d_in[4], WsuT,
        d_in[5], d_in[6], WcuT, d_in[8], WprojT,
        d_in[2], bqkv_c, d_in[9], bproj_c, flagp);
    // 1. fused convert + LayerNorm (gamma/beta raw)
    conv_ln_kernel<<<BL, blk, 0, stream>>>(d_in[0], d_in[10], d_in[11], x_c, xn, flagp);
    // 2. merged down-projections (silu)
    mfma_gemm_kernel<1><<<dim3(2, 32), blk, 0, stream>>>(x_c, 768, WdT, nullptr, nullptr, tdown, flagp, 256, 768);
    // 3. fused up-projections + gate -> d_out gate region + bf16 shadow
    gate_mfma_kernel<<<dim3(12, 64), blk, 0, stream>>>(tdown, WsuT, WcuT, d_in[7], d_out, gateb, flagp);
    // 4. qkv GEMM with fused elu/gate epilogue
    mfma_gemm_kernel<2><<<dim3(18, 32), blk, 0, stream>>>(xn, 768, WqkvT, bqkv_c, gateb, qkvt, flagp, 2304, 768);
    // 5. chunked causal linear attention (prefix inlined in scan)
    chunk_sum_mfma_kernel<<<BH * NC, blk, 0, stream>>>(qkvt, Msum, Zsum);
    chunk_scan_mfma_kernel<<<BH * NC, blk, 0, stream>>>(qkvt, Msum, Zsum, attnb);
    // 6. output projection (flagged store)
    mfma_gemm_kernel<3><<<dim3(6, 32), blk, 0, stream>>>(attnb, 768, WprojT, bproj_c, nullptr, d_out, flagp, 768, 768);
}

// Round 10
// 220.939 us; speedup vs baseline: 1.1439x; 1.0191x over previous
//
#include <hip/hip_runtime.h>

#define B_    2
#define L_    2048
#define D_    768
#define H_    12
#define BL    4096      // B_*L_
#define BH    24        // B_*H_
#define CHUNK 128
#define NC    16        // L_/CHUNK
#define GOFF  3145728   // element offset of gate output within d_out
#define PI_F  3.14159265358979f

typedef __bf16 bf16x8 __attribute__((ext_vector_type(8)));
typedef float  f32x4  __attribute__((ext_vector_type(4)));
typedef unsigned short us8 __attribute__((ext_vector_type(8)));

__device__ __forceinline__ float bf2f(unsigned short u) {
    return __uint_as_float(((unsigned int)u) << 16);
}
__device__ __forceinline__ unsigned short f2bf(float f) {
    unsigned int u = __float_as_uint(f);
    unsigned int r = (u + 0x7fffu + ((u >> 16) & 1u)) >> 16;
    return (unsigned short)r;
}
// fast transcendentals: hardware v_exp/v_log/v_cos/v_rcp paths
__device__ __forceinline__ float rcp_fast(float x) { return __builtin_amdgcn_rcpf(x); }
__device__ __forceinline__ float softplus_fast(float x) {
    return x > 20.f ? x : __logf(1.f + __expf(x));
}
__device__ __forceinline__ float tanh_fast(float x) {
    float e2 = __expf(2.f * x);               // inf for large x -> rcp -> 0 -> 1 (safe)
    return 1.f - 2.f * rcp_fast(e2 + 1.f);
}
// async global->LDS, 16B per lane; LDS dest = wave-uniform base + lane*16
__device__ __forceinline__ void dma16(const unsigned short* g, unsigned short* l) {
    __builtin_amdgcn_global_load_lds(
        (const __attribute__((address_space(1))) unsigned int*)g,
        (__attribute__((address_space(3))) unsigned int*)l, 16, 0, 0);
}
// per-block dtype self-detect: 1024 ushorts of x, outlier exponents => fp32
__device__ __forceinline__ int detect_local(const unsigned short* __restrict__ x,
                                            int* cnt_sh) {
    if (threadIdx.x == 0) *cnt_sh = 0;
    __syncthreads();
    int c = 0;
    #pragma unroll
    for (int i = 0; i < 4; i++) {
        unsigned short u = x[threadIdx.x * 4 + i];
        int e = (u >> 7) & 0xff;
        if (e < 100 || e > 140) c++;
    }
    atomicAdd(cnt_sh, c);
    __syncthreads();
    return *cnt_sh > 128;                     // >12.5% outliers => fp32
}

// ---------------- prep_all: weight transposes + bias converts + conv/LN -----------
// blocks [0,2892): weight prep; [2892, 2892+4096): convert+LayerNorm rows.
__global__ __launch_bounds__(256) void prep_all_kernel(
    const void* __restrict__ s0, unsigned short* __restrict__ dq,   // Wqkv 768x2304
    const void* __restrict__ s1, unsigned short* __restrict__ dd,   // Wsd -> WdT[0]
    const void* __restrict__ s2, unsigned short* __restrict__ dsu,  // Wsu 128x1536
    const void* __restrict__ s3,                                    // Wcd -> WdT[128*768]
    const void* __restrict__ s4, unsigned short* __restrict__ dcu,  // Wcu 128x1536
    const void* __restrict__ s5, unsigned short* __restrict__ dp,   // Wproj 768x768
    const void* __restrict__ sbq, unsigned short* __restrict__ dbq, // bqkv 2304
    const void* __restrict__ sbp, unsigned short* __restrict__ dbp, // bproj 768
    const void* __restrict__ xin,                                   // x
    const void* __restrict__ gr, const void* __restrict__ br,       // gamma, beta raw
    unsigned short* __restrict__ x_c, unsigned short* __restrict__ xn,
    int* __restrict__ flagp)
{
    __shared__ int cnt_sh;
    __shared__ unsigned short tile[32][33];   // prep path
    __shared__ float red[8];                  // LN path
    int fl = detect_local((const unsigned short*)xin, &cnt_sh);
    int id = blockIdx.x;
    int t = threadIdx.x;

    if (id >= 2892) {                         // ---- convert + LayerNorm path ----
        int row = id - 2892;
        if (row == 0 && t == 0) flagp[0] = fl;
        float v[3];
        #pragma unroll
        for (int j = 0; j < 3; j++) {
            int c = t + j * 256;
            v[j] = fl ? ((const float*)xin)[(size_t)row * D_ + c]
                      : bf2f(((const unsigned short*)xin)[(size_t)row * D_ + c]);
        }
        float s = v[0] + v[1] + v[2];
        #pragma unroll
        for (int m = 32; m >= 1; m >>= 1) s += __shfl_xor(s, m, 64);
        int wid = t >> 6;
        if ((t & 63) == 0) red[wid] = s;
        __syncthreads();
        float mean = (red[0] + red[1] + red[2] + red[3]) * (1.f / 768.f);
        float s2 = 0.f;
        #pragma unroll
        for (int j = 0; j < 3; j++) { float d = v[j] - mean; s2 += d * d; }
        #pragma unroll
        for (int m = 32; m >= 1; m >>= 1) s2 += __shfl_xor(s2, m, 64);
        if ((t & 63) == 0) red[4 + wid] = s2;
        __syncthreads();
        float var = (red[4] + red[5] + red[6] + red[7]) * (1.f / 768.f);
        float rs = rsqrtf(var + 1e-5f);
        #pragma unroll
        for (int j = 0; j < 3; j++) {
            int c = t + j * 256;
            float gv = fl ? ((const float*)gr)[c] : bf2f(((const unsigned short*)gr)[c]);
            float bv = fl ? ((const float*)br)[c] : bf2f(((const unsigned short*)br)[c]);
            x_c[(size_t)row * D_ + c] = f2bf(v[j]);
            float o = (v[j] - mean) * rs * gv + bv;
            xn[(size_t)row * D_ + c] = f2bf(o);
        }
        return;
    }
    if (id >= 2880) {                         // ---- bias converts ----
        const void* src; unsigned short* dst; int n, base;
        if (id < 2889) { src = sbq; dst = dbq; n = 2304; base = (id - 2880) * 256; }
        else           { src = sbp; dst = dbp; n = 768;  base = (id - 2889) * 256; }
        int i = base + t;
        if (i < n) dst[i] = fl ? f2bf(((const float*)src)[i]) : ((const unsigned short*)src)[i];
        return;
    }
    // ---- weight transpose path ----
    const void* src; unsigned short* dst; int K, N, tid;
    if (id < 1728)      { src = s0; dst = dq;  K = 768; N = 2304; tid = id; }
    else if (id < 1824) { src = s1; dst = dd;  K = 768; N = 128;  tid = id - 1728; }
    else if (id < 2016) { src = s2; dst = dsu; K = 128; N = 1536; tid = id - 1824; }
    else if (id < 2112) { src = s3; dst = dd + (size_t)128 * 768; K = 768; N = 128; tid = id - 2016; }
    else if (id < 2304) { src = s4; dst = dcu; K = 128; N = 1536; tid = id - 2112; }
    else                { src = s5; dst = dp;  K = 768; N = 768;  tid = id - 2304; }
    int tn = N / 32;
    int by = (tid / tn) * 32, bx = (tid % tn) * 32;
    int tx = t & 31, tyb = t >> 5;
    #pragma unroll
    for (int i = 0; i < 4; i++) {
        int k = by + tyb * 4 + i, n = bx + tx;
        size_t off = (size_t)k * N + n;
        tile[tyb * 4 + i][tx] = fl ? f2bf(((const float*)src)[off]) : ((const unsigned short*)src)[off];
    }
    __syncthreads();
    #pragma unroll
    for (int i = 0; i < 4; i++) {
        int n = bx + tyb * 4 + i, k = by + tx;
        dst[(size_t)n * K + k] = tile[tx][tyb * 4 + i];
    }
}

// ---------------- MFMA GEMM v4: TM-templated tiles (128 or 64 rows) ---------------
// TM x 128 tile, 4 waves in 2x2; each wave (TM/2) x 64 via (TM/32) x 4 mfma tiles.
// EPI: 0 bias, 1 silu, 2 qkv transform (gateb bf16), 3 flagged final store
template<int EPI, int TM>
__global__ __launch_bounds__(256) void mfma_gemm_kernel(
    const unsigned short* __restrict__ A, int lda,
    const unsigned short* __restrict__ BT,
    const unsigned short* __restrict__ bias,
    const unsigned short* __restrict__ gateb,
    void* __restrict__ outp,
    const int* __restrict__ flag,
    int N, int K)
{
    constexpr int MI = TM / 32;               // mfma row-tiles per wave
    constexpr int AOPS = TM / 32;             // dma16 ops per wave for A
    __shared__ unsigned short sbuf[17408];
    unsigned short* As = sbuf;                // [TM][64] swizzled
    unsigned short* Bs = sbuf + TM * 64;      // [128][64] swizzled
    unsigned short* Cs = sbuf;                // [TM][136] overlay

    int f = blockIdx.y * gridDim.x + blockIdx.x;
    int rps = gridDim.y >> 3;
    int strip = f & 7, within = f >> 3;
    int by = strip * rps + (within % rps);
    int bx = within / rps;
    int m0 = by * TM, n0 = bx * 128;

    int t = threadIdx.x;
    int lane = t & 63, wave = t >> 6, quad = lane >> 4, l16 = lane & 15;
    int wm = (wave & 1) * (TM / 2), wn = (wave >> 1) * 64;
    int xr = l16 & 7;

    int sr8 = lane >> 3;
    int scg = (lane & 7) ^ sr8;
    const unsigned short* ApL = A  + (size_t)(m0 + wave * (TM / 4) + sr8) * lda + scg * 8;
    const unsigned short* BpL = BT + (size_t)(n0 + wave * 32 + sr8) * K   + scg * 8;
    unsigned short* AsW = As + wave * (TM / 4) * 64;
    unsigned short* BsW = Bs + wave * 32 * 64;

    f32x4 acc[MI][4];
    #pragma unroll
    for (int i = 0; i < MI; i++)
        #pragma unroll
        for (int j = 0; j < 4; j++) acc[i][j] = (f32x4){0.f, 0.f, 0.f, 0.f};

    for (int k0 = 0; k0 < K; k0 += 64) {
        __syncthreads();
        #pragma unroll
        for (int c = 0; c < AOPS; c++)
            dma16(ApL + (size_t)(c * 8) * lda + k0, AsW + c * 512);
        #pragma unroll
        for (int c = 0; c < 4; c++)
            dma16(BpL + (size_t)(c * 8) * K + k0, BsW + c * 512);
        __syncthreads();
        #pragma unroll
        for (int ks = 0; ks < 2; ks++) {
            bf16x8 af[MI], bfr[4];
            #pragma unroll
            for (int i = 0; i < MI; i++)
                af[i] = *(const bf16x8*)&As[(wm + i * 16 + l16) * 64 + (((ks * 4 + quad) ^ xr) * 8)];
            #pragma unroll
            for (int j = 0; j < 4; j++)
                bfr[j] = *(const bf16x8*)&Bs[(wn + j * 16 + l16) * 64 + (((ks * 4 + quad) ^ xr) * 8)];
            #pragma unroll
            for (int i = 0; i < MI; i++)
                #pragma unroll
                for (int j = 0; j < 4; j++)
                    acc[i][j] = __builtin_amdgcn_mfma_f32_16x16x32_bf16(af[i], bfr[j], acc[i][j], 0, 0, 0);
        }
    }

    int fl = (EPI == 3) ? flag[0] : 0;
    __syncthreads();
    #pragma unroll
    for (int j = 0; j < 4; j++) {
        int col = n0 + wn + j * 16 + l16;
        float bv = bias ? bf2f(bias[col]) : 0.f;
        #pragma unroll
        for (int i = 0; i < MI; i++) {
            #pragma unroll
            for (int r = 0; r < 4; r++) {
                int row = m0 + wm + i * 16 + quad * 4 + r;
                float v = acc[i][j][r] + bv;
                if (EPI == 1) v = v * rcp_fast(1.f + __expf(-v));     // silu
                if (EPI == 2) {
                    if (col < D_) {
                        v = v > 0.f ? v + 1.f : __expf(v);             // elu+1
                    } else if (col < 2 * D_) {
                        float gg = bf2f(gateb[(size_t)row * D_ + (col - D_)]);
                        v *= (1.f + gg);
                        v = v > 0.f ? v + 1.f : __expf(v);
                    }
                }
                if (EPI == 3 && fl) {
                    ((float*)outp)[(size_t)row * N + col] = v;
                } else {
                    Cs[(wm + i * 16 + quad * 4 + r) * 136 + wn + j * 16 + l16] = f2bf(v);
                }
            }
        }
    }
    if (!(EPI == 3 && fl)) {
        __syncthreads();
        #pragma unroll
        for (int p = 0; p < TM / 16; p++) {
            int idx = p * 256 + t;
            int row = idx >> 4, cc = (idx & 15) * 8;
            *(us8*)&((unsigned short*)outp)[(size_t)(m0 + row) * N + n0 + cc] =
                *(const us8*)&Cs[row * 136 + cc];
        }
    }
}

// ---------------- Fused up-projections + gate, DMA-staged, fast transcendentals ---
__global__ __launch_bounds__(256) void gate_mfma_kernel(
    const unsigned short* __restrict__ tdown,
    const unsigned short* __restrict__ WsuT,
    const unsigned short* __restrict__ WcuT,
    const void* __restrict__ tempraw,
    void* __restrict__ dout,
    unsigned short* __restrict__ gateb,
    const int* __restrict__ flag)
{
    __shared__ unsigned short gbuf[17408];
    int f = blockIdx.y * gridDim.x + blockIdx.x;
    int rps = gridDim.y >> 3;
    int strip = f & 7, within = f >> 3;
    int by = strip * rps + (within % rps);
    int bx = within / rps;
    int m0 = by * 64, c0 = bx * 64;

    int t = threadIdx.x;
    int lane = t & 63, wave = t >> 6, quad = lane >> 4, l16 = lane & 15;
    int xg = l16 & 3;

    int r_t = wave * 16 + (lane >> 2);
    int g_t = (lane & 3) ^ ((lane >> 2) & 3);
    const unsigned short* s0 = tdown + (size_t)(m0 + r_t) * 256 + g_t * 8;
    const unsigned short* s1 = s0 + 128;
    const unsigned short* s2 = WsuT + (size_t)(c0 + r_t) * 128 + g_t * 8;
    const unsigned short* s3 = WsuT + (size_t)(768 + c0 + r_t) * 128 + g_t * 8;
    const unsigned short* s4 = WcuT + (size_t)(c0 + r_t) * 128 + g_t * 8;
    const unsigned short* s5 = WcuT + (size_t)(768 + c0 + r_t) * 128 + g_t * 8;
    unsigned short* ldq = gbuf + wave * 512;

    f32x4 acc[4][4];
    #pragma unroll
    for (int i = 0; i < 4; i++)
        #pragma unroll
        for (int j = 0; j < 4; j++) acc[i][j] = (f32x4){0.f, 0.f, 0.f, 0.f};

    int Atile = wave >> 1, Btile = 2 + wave;
    for (int k0 = 0; k0 < 128; k0 += 32) {
        __syncthreads();
        dma16(s0 + k0, ldq + 0 * 2048);
        dma16(s1 + k0, ldq + 1 * 2048);
        dma16(s2 + k0, ldq + 2 * 2048);
        dma16(s3 + k0, ldq + 3 * 2048);
        dma16(s4 + k0, ldq + 4 * 2048);
        dma16(s5 + k0, ldq + 5 * 2048);
        __syncthreads();
        bf16x8 af[4], bfr[4];
        #pragma unroll
        for (int i = 0; i < 4; i++)
            af[i] = *(const bf16x8*)&gbuf[Atile * 2048 + (i * 16 + l16) * 32 + ((quad ^ xg) * 8)];
        #pragma unroll
        for (int j = 0; j < 4; j++)
            bfr[j] = *(const bf16x8*)&gbuf[Btile * 2048 + (j * 16 + l16) * 32 + ((quad ^ xg) * 8)];
        #pragma unroll
        for (int i = 0; i < 4; i++)
            #pragma unroll
            for (int j = 0; j < 4; j++)
                acc[i][j] = __builtin_amdgcn_mfma_f32_16x16x32_bf16(af[i], bfr[j], acc[i][j], 0, 0, 0);
    }
    __syncthreads();
    #pragma unroll
    for (int i = 0; i < 4; i++)
        #pragma unroll
        for (int j = 0; j < 4; j++)
            #pragma unroll
            for (int r = 0; r < 4; r++)
                gbuf[wave * 4352 + (i * 16 + quad * 4 + r) * 68 + j * 16 + l16] = f2bf(acc[i][j][r]);
    __syncthreads();
    int fl = flag[0];
    float tempv = fl ? ((const float*)tempraw)[0] : bf2f(((const unsigned short*)tempraw)[0]);
    #pragma unroll
    for (int p = 0; p < 16; p++) {
        int idx = p * 256 + t;
        int row = idx >> 6, col = idx & 63;
        float sa = softplus_fast(bf2f(gbuf[0 * 4352 + row * 68 + col]));
        float sp = tanh_fast(bf2f(gbuf[1 * 4352 + row * 68 + col]));
        float ca = softplus_fast(bf2f(gbuf[2 * 4352 + row * 68 + col]));
        float cp = tanh_fast(bf2f(gbuf[3 * 4352 + row * 68 + col]));
        float inter = sa * ca * __cosf(PI_F * (sp - cp)) * tempv;
        float g = rcp_fast(1.f + __expf(-inter));
        size_t off = (size_t)GOFF + (size_t)(m0 + row) * D_ + c0 + col;
        unsigned short gb = f2bf(g);
        if (fl) ((float*)dout)[off] = g;
        else    ((unsigned short*)dout)[off] = gb;
        gateb[(size_t)(m0 + row) * D_ + c0 + col] = gb;
    }
}

// ---------------- Pass A (MFMA): raw per-chunk S_c = K^T . V_ext ------------------
__global__ __launch_bounds__(256) void chunk_sum_mfma_kernel(
    const unsigned short* __restrict__ qkvt,
    float* __restrict__ Msum, float* __restrict__ Zsum)
{
    __shared__ __align__(16) unsigned short KT[64 * 136];
    __shared__ __align__(16) unsigned short VT[80 * 136];
    int blk = blockIdx.x;
    int bh = blk / NC, cc = blk - bh * NC;
    int b = bh / H_, h = bh - b * H_;
    int t = threadIdx.x;
    int lane = t & 63, wave = t >> 6, quad = lane >> 4, l16 = lane & 15;
    int lr = t >> 1, lc = (t & 1) * 32;
    size_t rowbase = (size_t)(b * L_ + cc * CHUNK);
    const unsigned short* kg = qkvt + rowbase * 2304 + D_ + h * 64;
    const unsigned short* vg = qkvt + rowbase * 2304 + 2 * D_ + h * 64;
    #pragma unroll
    for (int c = 0; c < 4; c++) {
        us8 kv = *(const us8*)&kg[(size_t)lr * 2304 + lc + c * 8];
        us8 vv = *(const us8*)&vg[(size_t)lr * 2304 + lc + c * 8];
        #pragma unroll
        for (int ii = 0; ii < 8; ii++) {
            KT[(lc + c * 8 + ii) * 136 + lr] = kv[ii];
            VT[(lc + c * 8 + ii) * 136 + lr] = vv[ii];
        }
    }
    if (t < 128) VT[64 * 136 + t] = 0x3F80;   // ones row (bf16 1.0)
    __syncthreads();

    f32x4 acc[5];
    #pragma unroll
    for (int j = 0; j < 5; j++) acc[j] = (f32x4){0.f, 0.f, 0.f, 0.f};
    #pragma unroll
    for (int ks = 0; ks < 4; ks++) {
        bf16x8 a = *(const bf16x8*)&KT[(wave * 16 + l16) * 136 + ks * 32 + quad * 8];
        #pragma unroll
        for (int j = 0; j < 5; j++) {
            bf16x8 bv = *(const bf16x8*)&VT[(j * 16 + l16) * 136 + ks * 32 + quad * 8];
            acc[j] = __builtin_amdgcn_mfma_f32_16x16x32_bf16(a, bv, acc[j], 0, 0, 0);
        }
    }
    float* mo = Msum + (size_t)blk * 4096;
    #pragma unroll
    for (int j = 0; j < 4; j++)
        #pragma unroll
        for (int r = 0; r < 4; r++)
            mo[(wave * 16 + quad * 4 + r) * 64 + j * 16 + l16] = acc[j][r];
    if (l16 == 0) {
        #pragma unroll
        for (int r = 0; r < 4; r++)
            Zsum[(size_t)blk * 64 + wave * 16 + quad * 4 + r] = acc[4][r];
    }
}

// ---------------- Pass C (MFMA): inlined prefix + O = Q.S + tril(QK^T).V ----------
__global__ __launch_bounds__(256) void chunk_scan_mfma_kernel(
    const unsigned short* __restrict__ qkvt,
    const float* __restrict__ Msum, const float* __restrict__ Zsum,
    unsigned short* __restrict__ attnb)
{
    __shared__ __align__(16) unsigned short sbuf[34048];
    unsigned short* Qs = sbuf;                  // [128][64] swizzled
    unsigned short* Ks = sbuf + 8192;           // [128][64] swizzled
    unsigned short* Ps = sbuf;                  // [128][136]
    unsigned short* VT = sbuf + 17408;          // [80][136]
    unsigned short* Ss = sbuf + 28288;          // [80][72]
    unsigned short* Cout = sbuf;                // [128][136]

    int blk = blockIdx.x;
    int bh = blk / NC, cc = NC - 1 - (blk - bh * NC);   // heavy blocks first
    int b = bh / H_, h = bh - b * H_;
    int t = threadIdx.x;
    int lane = t & 63, wave = t >> 6, quad = lane >> 4, l16 = lane & 15;
    int wm = wave * 32;
    int xr = l16 & 7;
    size_t rowbase = (size_t)(b * L_ + cc * CHUNK);
    const unsigned short* qg = qkvt + rowbase * 2304 + h * 64;
    const unsigned short* kg = qkvt + rowbase * 2304 + D_ + h * 64;
    const unsigned short* vg = qkvt + rowbase * 2304 + 2 * D_ + h * 64;

    // ---- DMA-stage Q,K (swizzled [128][64]) ----
    int r8 = lane >> 3, g8 = (lane & 7) ^ r8;
    #pragma unroll
    for (int s = 0; s < 8; s++) {
        int op = s * 4 + wave;                  // 0..31
        int tl = op >> 4, o16 = op & 15;
        const unsigned short* src = (tl ? kg : qg) + (size_t)(o16 * 8 + r8) * 2304 + g8 * 8;
        unsigned short* dst = (tl ? Ks : Qs) + o16 * 512;
        dma16(src, dst);
    }
    // ---- V transpose (scalar) ----
    {
        int lr = t >> 1, lc = (t & 1) * 32;
        #pragma unroll
        for (int c = 0; c < 4; c++) {
            us8 vv = *(const us8*)&vg[(size_t)lr * 2304 + lc + c * 8];
            #pragma unroll
            for (int ii = 0; ii < 8; ii++)
                VT[(lc + c * 8 + ii) * 136 + lr] = vv[ii];
        }
    }
    if (t < 128) VT[64 * 136 + t] = 0x3F80;     // ones row
    // ---- inlined exclusive prefix over chunks (fp32) ----
    {
        int d = t & 63, jb = (t >> 6) * 16;
        float a16[16];
        #pragma unroll
        for (int j = 0; j < 16; j++) a16[j] = 0.f;
        for (int c = 0; c < cc; c++) {
            const float* mp = Msum + ((size_t)bh * NC + c) * 4096 + d * 64 + jb;
            #pragma unroll
            for (int g4 = 0; g4 < 4; g4++) {
                float4 sv = *(const float4*)&mp[g4 * 4];
                a16[g4 * 4 + 0] += sv.x; a16[g4 * 4 + 1] += sv.y;
                a16[g4 * 4 + 2] += sv.z; a16[g4 * 4 + 3] += sv.w;
            }
        }
        #pragma unroll
        for (int j = 0; j < 16; j++) Ss[(jb + j) * 72 + d] = f2bf(a16[j]);
    }
    if (t < 64) {
        float rz = 0.f;
        for (int c = 0; c < cc; c++) rz += Zsum[((size_t)bh * NC + c) * 64 + t];
        Ss[64 * 72 + t] = f2bf(rz);
    }
    __syncthreads();

    f32x4 Pacc[2][8], Oacc[2][5];
    #pragma unroll
    for (int i = 0; i < 2; i++) {
        #pragma unroll
        for (int n = 0; n < 8; n++) Pacc[i][n] = (f32x4){0.f, 0.f, 0.f, 0.f};
        #pragma unroll
        for (int j = 0; j < 5; j++) Oacc[i][j] = (f32x4){0.f, 0.f, 0.f, 0.f};
    }
    bf16x8 aq[2][2];
    #pragma unroll
    for (int i = 0; i < 2; i++)
        #pragma unroll
        for (int ks = 0; ks < 2; ks++)
            aq[i][ks] = *(const bf16x8*)&Qs[(wm + i * 16 + l16) * 64 + (((ks * 4 + quad) ^ xr) * 8)];
    #pragma unroll
    for (int n = 0; n < 8; n++)
        #pragma unroll
        for (int ks = 0; ks < 2; ks++) {
            bf16x8 bk = *(const bf16x8*)&Ks[(n * 16 + l16) * 64 + (((ks * 4 + quad) ^ xr) * 8)];
            #pragma unroll
            for (int i = 0; i < 2; i++)
                Pacc[i][n] = __builtin_amdgcn_mfma_f32_16x16x32_bf16(aq[i][ks], bk, Pacc[i][n], 0, 0, 0);
        }
    #pragma unroll
    for (int j = 0; j < 5; j++)
        #pragma unroll
        for (int ks = 0; ks < 2; ks++) {
            bf16x8 bs = *(const bf16x8*)&Ss[(j * 16 + l16) * 72 + ks * 32 + quad * 8];
            #pragma unroll
            for (int i = 0; i < 2; i++)
                Oacc[i][j] = __builtin_amdgcn_mfma_f32_16x16x32_bf16(aq[i][ks], bs, Oacc[i][j], 0, 0, 0);
        }
    __syncthreads();   // Q,K,S reads done — overlay P

    #pragma unroll
    for (int i = 0; i < 2; i++)
        #pragma unroll
        for (int n = 0; n < 8; n++)
            #pragma unroll
            for (int r = 0; r < 4; r++) {
                int trow = wm + i * 16 + quad * 4 + r;
                int scol = n * 16 + l16;
                Ps[trow * 136 + scol] = (scol <= trow) ? f2bf(Pacc[i][n][r]) : 0;
            }
    __syncthreads();

    #pragma unroll
    for (int ks = 0; ks < 4; ks++) {
        bf16x8 ap[2];
        #pragma unroll
        for (int i = 0; i < 2; i++)
            ap[i] = *(const bf16x8*)&Ps[(wm + i * 16 + l16) * 136 + ks * 32 + quad * 8];
        #pragma unroll
        for (int j = 0; j < 5; j++) {
            bf16x8 bv = *(const bf16x8*)&VT[(j * 16 + l16) * 136 + ks * 32 + quad * 8];
            #pragma unroll
            for (int i = 0; i < 2; i++)
                Oacc[i][j] = __builtin_amdgcn_mfma_f32_16x16x32_bf16(ap[i], bv, Oacc[i][j], 0, 0, 0);
        }
    }
    __syncthreads();   // P reads done — overlay Cout

    #pragma unroll
    for (int i = 0; i < 2; i++) {
        #pragma unroll
        for (int r = 0; r < 4; r++) {
            float den = __shfl(Oacc[i][4][r], lane & 48) + 1e-6f;
            float inv = 1.f / den;
            #pragma unroll
            for (int j = 0; j < 4; j++)
                Cout[(wm + i * 16 + quad * 4 + r) * 136 + j * 16 + l16] = f2bf(Oacc[i][j][r] * inv);
        }
    }
    __syncthreads();
    unsigned short* abase = attnb + rowbase * D_ + h * 64;
    #pragma unroll
    for (int p = 0; p < 4; p++) {
        int idx = p * 256 + t;
        int row = idx >> 3, cg = (idx & 7) * 8;
        *(us8*)&abase[(size_t)row * D_ + cg] = *(const us8*)&Cout[row * 136 + cg];
    }
}

extern "C" void kernel_launch(void* const* d_in, const int* in_sizes, int n_in,
                              void* d_out, int out_size, void* d_ws, size_t ws_size,
                              hipStream_t stream)
{
    char* w = (char*)d_ws;
    auto alloc = [&](size_t bytes) { void* p = (void*)w; w += (bytes + 255) & ~(size_t)255; return p; };
    int*            flagp   = (int*)alloc(256);
    unsigned short* x_c     = (unsigned short*)alloc((size_t)BL * D_ * 2);   // reused as attnb
    unsigned short* attnb   = x_c;
    unsigned short* xn      = (unsigned short*)alloc((size_t)BL * D_ * 2);
    unsigned short* WqkvT   = (unsigned short*)alloc((size_t)2304 * 768 * 2);
    unsigned short* WdT     = (unsigned short*)alloc((size_t)256 * 768 * 2);
    unsigned short* WsuT    = (unsigned short*)alloc((size_t)1536 * 128 * 2);
    unsigned short* WcuT    = (unsigned short*)alloc((size_t)1536 * 128 * 2);
    unsigned short* WprojT  = (unsigned short*)alloc((size_t)768 * 768 * 2);
    unsigned short* bqkv_c  = (unsigned short*)alloc((size_t)2304 * 2);
    unsigned short* bproj_c = (unsigned short*)alloc((size_t)768 * 2);
    unsigned short* tdown   = (unsigned short*)alloc((size_t)BL * 256 * 2);
    float*          Zsum    = (float*)alloc((size_t)BH * NC * 64 * 4);
    unsigned short* qkvt    = (unsigned short*)alloc((size_t)BL * 2304 * 2);
    float*          Msum    = (float*)alloc((size_t)BH * NC * 4096 * 4);
    // gateb aliases Msum: gate writes @t2, qkv reads @t3; Msum written @t4.
    unsigned short* gateb   = (unsigned short*)Msum;

    dim3 blk(256);
    // 0. fused weight-prep + convert/LN (self-detecting; block 2892 publishes flag)
    prep_all_kernel<<<2892 + BL, blk, 0, stream>>>(
        d_in[1], WqkvT, d_in[3], WdT, d_in[4], WsuT,
        d_in[5], d_in[6], WcuT, d_in[8], WprojT,
        d_in[2], bqkv_c, d_in[9], bproj_c,
        d_in[0], d_in[10], d_in[11], x_c, xn, flagp);
    // 1. merged down-projections (silu) — TM=64 for 2x grid
    mfma_gemm_kernel<1, 64><<<dim3(2, 64), blk, 0, stream>>>(x_c, 768, WdT, nullptr, nullptr, tdown, flagp, 256, 768);
    // 2. fused up-projections + gate -> d_out gate region + bf16 shadow
    gate_mfma_kernel<<<dim3(12, 64), blk, 0, stream>>>(tdown, WsuT, WcuT, d_in[7], d_out, gateb, flagp);
    // 3. qkv GEMM with fused elu/gate epilogue
    mfma_gemm_kernel<2, 128><<<dim3(18, 32), blk, 0, stream>>>(xn, 768, WqkvT, bqkv_c, gateb, qkvt, flagp, 2304, 768);
    // 4. chunked causal linear attention (prefix inlined in scan)
    chunk_sum_mfma_kernel<<<BH * NC, blk, 0, stream>>>(qkvt, Msum, Zsum);
    chunk_scan_mfma_kernel<<<BH * NC, blk, 0, stream>>>(qkvt, Msum, Zsum, attnb);
    // 5. output projection (flagged store) — TM=64 for 2x grid
    mfma_gemm_kernel<3, 64><<<dim3(6, 64), blk, 0, stream>>>(attnb, 768, WprojT, bproj_c, nullptr, d_out, flagp, 768, 768);
}